// Round 3
// baseline (2887.236 us; speedup 1.0000x reference)
//
#include <hip/hip_runtime.h>
#include <hip/hip_bf16.h>

typedef __hip_bfloat16 bf16;
typedef unsigned short u16;

#define LEAK 0.1f
#define EPS_ 1e-5f
// N=32 C=64 T=400 V=27 S=2 IC=16 O=64 -- all inputs/outputs fp32

__device__ __forceinline__ float u2f(u16 u) { return __uint_as_float(((unsigned int)u) << 16); }
__device__ __forceinline__ u16 f2u(float f) {
  bf16 h = __float2bfloat16(f);
  u16 r;
  __builtin_memcpy(&r, &h, 2);
  return r;
}

// ---------------------------------------------------------------------------
// K1: att_acc[n,s,u,v] += sum_{c in 16, t in chunk} q[n,s,c,t,u]*k[n,s,c,t,v]
// where qk = W_in @ (x + pe). Grid: (16 t-chunks of 25, N). Block 256.
// ---------------------------------------------------------------------------
__global__ __launch_bounds__(256) void k_att_acc(
    const float* __restrict__ x, const float* __restrict__ pe,
    const float* __restrict__ W_in, const float* __restrict__ b_in,
    float* __restrict__ att)
{
  __shared__ float sW[64 * 64];
  __shared__ float sb[64];
  __shared__ float sy[64 * 27];   // y = x + pe, [c][v]
  __shared__ float sqk[64 * 27];  // qk rows, [r][v]
  const int tid = threadIdx.x;
  const int n = blockIdx.y;
  const int t0 = blockIdx.x * 25;

  for (int i = tid; i < 64 * 64; i += 256) sW[i] = W_in[i];
  if (tid < 64) sb[tid] = b_in[tid];

  // each thread owns up to 6 (s,u,v) accumulator cells (2*729 = 1458 total)
  float acc[6];
  int ps[6], pu[6], pv[6];
#pragma unroll
  for (int k2 = 0; k2 < 6; ++k2) {
    acc[k2] = 0.f;
    int p = tid + k2 * 256;
    if (p < 1458) { ps[k2] = p / 729; int r = p % 729; pu[k2] = r / 27; pv[k2] = r % 27; }
    else ps[k2] = -1;
  }
  __syncthreads();

  for (int t = t0; t < t0 + 25; ++t) {
    for (int i = tid; i < 64 * 27; i += 256) {
      int c = i / 27, v = i % 27;
      sy[i] = x[((n * 64 + c) * 400 + t) * 27 + v] + pe[(c * 400 + t) * 27 + v];
    }
    __syncthreads();
    for (int i = tid; i < 64 * 27; i += 256) {
      int r = i / 27, v = i % 27;
      float a = sb[r];
#pragma unroll
      for (int c = 0; c < 64; ++c) a += sW[r * 64 + c] * sy[c * 27 + v];
      sqk[i] = a;
    }
    __syncthreads();
#pragma unroll
    for (int k2 = 0; k2 < 6; ++k2) {
      if (ps[k2] >= 0) {
        const int qb = (ps[k2] * 16) * 27;       // q rows: s*16 + j
        const int kb = (32 + ps[k2] * 16) * 27;  // k rows: 32 + s*16 + j
        float a = acc[k2];
#pragma unroll
        for (int j = 0; j < 16; ++j)
          a += sqk[qb + j * 27 + pu[k2]] * sqk[kb + j * 27 + pv[k2]];
        acc[k2] = a;
      }
    }
    __syncthreads();
  }
#pragma unroll
  for (int k2 = 0; k2 < 6; ++k2)
    if (ps[k2] >= 0)
      atomicAdd(&att[((n * 2 + ps[k2]) * 27 + pu[k2]) * 27 + pv[k2]], acc[k2]);
}

// ---------------------------------------------------------------------------
// K1b: att = tanh(acc/6400)*alphas[s] + att0[s,u,v]   (in place)
// ---------------------------------------------------------------------------
__global__ __launch_bounds__(256) void k_att_fin(
    float* __restrict__ att, const float* __restrict__ alphas,
    const float* __restrict__ att0)
{
  int i = blockIdx.x * 256 + threadIdx.x;
  if (i >= 32 * 2 * 729) return;
  int s = (i / 729) & 1;
  int r = i % 729;
  att[i] = tanhf(att[i] * (1.f / 6400.f)) * alphas[s] + att0[s * 729 + r];
}

// ---------------------------------------------------------------------------
// K2 (fused): per block = (n, 4 center t-slices + 1 halo slice each side).
//   slice loop (6 slices): y2 = att-apply(x) ; y3 = lrelu(x + bn(W_out@y2))
//                          y4 = lrelu(x + bn(W_ff@y3))   [all in LDS]
//   then: z = lrelu(y4 + bn(conv3_t(y4) + b_t)) -> fp32 out (4 center slices)
// LDS intermediates bf16-compressed (error << 0.2475 threshold). 62.6 KB.
// ---------------------------------------------------------------------------
__global__ __launch_bounds__(256) void k_fused(
    const float* __restrict__ x, const float* __restrict__ att,
    const float* __restrict__ W_out, const float* __restrict__ b_out,
    const float* __restrict__ g_out, const float* __restrict__ be_out,
    const float* __restrict__ m_out, const float* __restrict__ v_out,
    const float* __restrict__ W_ff, const float* __restrict__ b_ff,
    const float* __restrict__ g_ff, const float* __restrict__ be_ff,
    const float* __restrict__ m_ff, const float* __restrict__ v_ff,
    const float* __restrict__ W_t, const float* __restrict__ b_t,
    const float* __restrict__ g_t, const float* __restrict__ be_t,
    const float* __restrict__ m_t, const float* __restrict__ v_t,
    float* __restrict__ out)
{
  __shared__ float satt[2 * 729];   // 5832 B
  __shared__ u16 sx[64 * 6 * 27];   // 20736 B  x (bf16 bits), [c][st][v], st=t-(t0-1)
  __shared__ u16 sy4[64 * 6 * 27];  // 20736 B  y4 (bf16 bits)
  __shared__ u16 sy2[128 * 27];     // 6912 B   per-slice y2 (bf16 bits), [s*64+c][v]
  __shared__ float sy3[64 * 27];    // 6912 B   per-slice y3 (fp32)
  __shared__ float sAo[64], sBo[64], sAf[64], sBf[64], sAt[64], sBt[64];  // 1536 B

  const int tid = threadIdx.x;
  const int n = blockIdx.y;
  const int t0 = blockIdx.x * 4;

  for (int i = tid; i < 1458; i += 256) satt[i] = att[n * 1458 + i];
  for (int i = tid; i < 64 * 162; i += 256) {
    int c = i / 162, r = i % 162, st = r / 27, vv = r % 27;
    int t = t0 + st - 1;
    sx[i] = (t >= 0 && t < 400) ? f2u(x[((n * 64 + c) * 400 + t) * 27 + vv]) : (u16)0;
  }
  if (tid < 64) {
    float sc = g_out[tid] * rsqrtf(v_out[tid] + EPS_);
    sAo[tid] = sc;
    sBo[tid] = (b_out[tid] - m_out[tid]) * sc + be_out[tid];
  } else if (tid < 128) {
    int o = tid - 64;
    float sc = g_ff[o] * rsqrtf(v_ff[o] + EPS_);
    sAf[o] = sc;
    sBf[o] = (b_ff[o] - m_ff[o]) * sc + be_ff[o];
  } else if (tid < 192) {
    int o = tid - 128;
    float sc = g_t[o] * rsqrtf(v_t[o] + EPS_);
    sAt[o] = sc;
    sBt[o] = (b_t[o] - m_t[o]) * sc + be_t[o];
  }
  __syncthreads();

  for (int st = 0; st < 6; ++st) {
    const int t = t0 + st - 1;
    const bool valid = (t >= 0 && t < 400);  // uniform across block
    if (valid) {
      // y2[s*64+c][v] = sum_u x[c][t][u] * att[s][u][v]
      for (int i = tid; i < 128 * 27; i += 256) {
        int sc = i / 27, vv = i % 27;
        int s = sc >> 6, c = sc & 63;
        const u16* xr = &sx[c * 162 + st * 27];
        const float* ar = &satt[s * 729];
        float a = 0.f;
#pragma unroll
        for (int u = 0; u < 27; ++u) a += u2f(xr[u]) * ar[u * 27 + vv];
        sy2[i] = f2u(a);
      }
    } else {
      // conv zero-padding: y4 = 0 for out-of-range slices
      for (int i = tid; i < 64 * 27; i += 256) {
        int c = i / 27, vv = i % 27;
        sy4[c * 162 + st * 27 + vv] = 0;
      }
    }
    __syncthreads();
    if (valid) {
      // y3[o][v] = lrelu(x + bn(W_out @ y2))
      for (int i = tid; i < 64 * 27; i += 256) {
        int o = i / 27, vv = i % 27;
        const float* wr = &W_out[o * 128];
        float a = 0.f;
#pragma unroll 16
        for (int sc = 0; sc < 128; ++sc) a += wr[sc] * u2f(sy2[sc * 27 + vv]);
        float r = u2f(sx[o * 162 + st * 27 + vv]) + a * sAo[o] + sBo[o];
        sy3[i] = (r >= 0.f) ? r : LEAK * r;
      }
    }
    __syncthreads();
    if (valid) {
      // y4[o][v] = lrelu(x + bn(W_ff @ y3))
      for (int i = tid; i < 64 * 27; i += 256) {
        int o = i / 27, vv = i % 27;
        const float* wr = &W_ff[o * 64];
        float a = 0.f;
#pragma unroll 16
        for (int c = 0; c < 64; ++c) a += wr[c] * sy3[c * 27 + vv];
        float r = u2f(sx[o * 162 + st * 27 + vv]) + a * sAf[o] + sBf[o];
        sy4[o * 162 + st * 27 + vv] = f2u((r >= 0.f) ? r : LEAK * r);
      }
    }
    __syncthreads();
  }

  // temporal conv: o = tid>>2 (64), q = tid&3 (4 center slices)
  const int o = tid >> 2, q = tid & 3;
  float acc[27];
#pragma unroll
  for (int vv = 0; vv < 27; ++vv) acc[vv] = 0.f;
  for (int i = 0; i < 64; ++i) {
    float w0 = W_t[(o * 64 + i) * 3 + 0];
    float w1 = W_t[(o * 64 + i) * 3 + 1];
    float w2 = W_t[(o * 64 + i) * 3 + 2];
    const u16* r0 = &sy4[i * 162 + q * 27];  // st=q is (center-1); +27 center; +54 (center+1)
#pragma unroll
    for (int vv = 0; vv < 27; ++vv)
      acc[vv] += w0 * u2f(r0[vv]) + w1 * u2f(r0[27 + vv]) + w2 * u2f(r0[54 + vv]);
  }
  const float A = sAt[o], B = sBt[o];
#pragma unroll
  for (int vv = 0; vv < 27; ++vv) {
    float r = u2f(sy4[o * 162 + (q + 1) * 27 + vv]) + acc[vv] * A + B;
    r = (r >= 0.f) ? r : LEAK * r;
    out[((n * 64 + o) * 400 + t0 + q) * 27 + vv] = r;
  }
}

// ---------------------------------------------------------------------------
extern "C" void kernel_launch(void* const* d_in, const int* in_sizes, int n_in,
                              void* d_out, int out_size, void* d_ws, size_t ws_size,
                              hipStream_t stream)
{
  const float* x      = (const float*)d_in[0];
  const float* pe     = (const float*)d_in[1];
  const float* W_in   = (const float*)d_in[2];
  const float* b_in   = (const float*)d_in[3];
  const float* alphas = (const float*)d_in[4];
  const float* att0   = (const float*)d_in[5];
  const float* W_out  = (const float*)d_in[6];
  const float* b_out  = (const float*)d_in[7];
  const float* g_out  = (const float*)d_in[8];
  const float* be_out = (const float*)d_in[9];
  const float* m_out  = (const float*)d_in[10];
  const float* v_out  = (const float*)d_in[11];
  const float* W_ff   = (const float*)d_in[12];
  const float* b_ff   = (const float*)d_in[13];
  const float* g_ff   = (const float*)d_in[14];
  const float* be_ff  = (const float*)d_in[15];
  const float* m_ff   = (const float*)d_in[16];
  const float* v_ff   = (const float*)d_in[17];
  const float* W_t    = (const float*)d_in[18];
  const float* b_t    = (const float*)d_in[19];
  const float* g_t    = (const float*)d_in[20];
  const float* be_t   = (const float*)d_in[21];
  const float* m_t    = (const float*)d_in[22];
  const float* v_t    = (const float*)d_in[23];

  float* att = (float*)d_ws;  // 32*2*729 floats = 186 KB — only ws use

  hipMemsetAsync(att, 0, 32 * 2 * 729 * sizeof(float), stream);
  k_att_acc<<<dim3(16, 32), 256, 0, stream>>>(x, pe, W_in, b_in, att);
  k_att_fin<<<dim3((32 * 2 * 729 + 255) / 256), 256, 0, stream>>>(att, alphas, att0);
  k_fused<<<dim3(100, 32), 256, 0, stream>>>(
      x, att,
      W_out, b_out, g_out, be_out, m_out, v_out,
      W_ff, b_ff, g_ff, be_ff, m_ff, v_ff,
      W_t, b_t, g_t, be_t, m_t, v_t,
      (float*)d_out);
}

// Round 4
// 439.813 us; speedup vs baseline: 6.5647x; 6.5647x over previous
//
#include <hip/hip_runtime.h>
#include <hip/hip_bf16.h>

typedef __hip_bfloat16 bf16;
typedef unsigned short u16;
typedef __attribute__((ext_vector_type(8))) short short8;
typedef __attribute__((ext_vector_type(4))) float f32x4;

#define LEAK 0.1f
#define EPS_ 1e-5f
#define MFMA(a, b, c) __builtin_amdgcn_mfma_f32_16x16x32_bf16(a, b, c, 0, 0, 0)
// N=32 C=64 T=400 V=27 S=2 IC=16 O=64 -- all inputs/outputs fp32

__device__ __forceinline__ float u2f(u16 u) { return __uint_as_float(((unsigned int)u) << 16); }
__device__ __forceinline__ u16 f2u(float f) {
  bf16 h = __float2bfloat16(f);
  u16 r;
  __builtin_memcpy(&r, &h, 2);
  return r;
}
__device__ __forceinline__ f32x4 z4() { f32x4 z = {0.f, 0.f, 0.f, 0.f}; return z; }

// ---------------------------------------------------------------------------
// K1 (MFMA): att logits. Per block: (n, 16 t-slices). 4 waves.
// Per slice: qk = W_in@(x+pe)+b (wave w owns 16 rows), then logit QK^T
// accumulation (wave w owns (s=w>>1, u-tile=w&1)). C-frags accumulate across
// slices in registers; atomicAdd once at block end.
// ---------------------------------------------------------------------------
__global__ __launch_bounds__(256) void k_att_mfma(
    const float* __restrict__ x, const float* __restrict__ pe,
    const float* __restrict__ W_in, const float* __restrict__ b_in,
    float* __restrict__ att)
{
  __shared__ u16 syT[32][72];   // (x+pe)^T: [v][c]; rows 27..31 stay zero
  __shared__ u16 sqkT[32][72];  // qk^T: [v][r];    rows 27..31 stay zero
  const int tid = threadIdx.x;
  const int w = tid >> 6, lane = tid & 63;
  const int m = lane & 15, quad = lane >> 4;
  const int n = blockIdx.y, t0 = blockIdx.x * 16;
  const int s_w = w >> 1, mtu = w & 1;

  for (int i = tid; i < 32 * 72; i += 256) { syT[0][i] = 0; sqkT[0][i] = 0; }

  // persistent W_in A-frags for wave's qk row-tile (rows 16w..16w+15)
  short8 aW[2];
#pragma unroll
  for (int kf = 0; kf < 2; ++kf) {
    short8 tt;
#pragma unroll
    for (int j = 0; j < 8; ++j)
      tt[j] = (short)f2u(W_in[(16 * w + m) * 64 + 32 * kf + 8 * quad + j]);
    aW[kf] = tt;
  }
  float bb[4];
#pragma unroll
  for (int r = 0; r < 4; ++r) bb[r] = b_in[16 * w + quad * 4 + r];
  f32x4 accA0 = z4(), accA1 = z4();  // logit C-frags (nt=0,1)
  __syncthreads();

  for (int sl = 0; sl < 16; ++sl) {
    const int t = t0 + sl;
    // S1: stage y = x + pe into syT[v][c]
    for (int i = tid; i < 1728; i += 256) {
      int c = i / 27, v = i % 27;
      syT[v][c] = f2u(x[((n * 64 + c) * 400 + t) * 27 + v] + pe[(c * 400 + t) * 27 + v]);
    }
    __syncthreads();
    // S2: qk GEMM (M-tile = wave), epilogue writes sqkT[v][r] with bias
    {
      f32x4 a0 = z4(), a1 = z4();
#pragma unroll
      for (int kf = 0; kf < 2; ++kf) {
        short8 b0 = *(const short8*)&syT[m][32 * kf + 8 * quad];
        short8 b1 = *(const short8*)&syT[16 + m][32 * kf + 8 * quad];
        a0 = MFMA(aW[kf], b0, a0);
        a1 = MFMA(aW[kf], b1, a1);
      }
#pragma unroll
      for (int nt = 0; nt < 2; ++nt) {
        f32x4 a = nt ? a1 : a0;
        int v = 16 * nt + m;
        if (v < 27) {
#pragma unroll
          for (int reg = 0; reg < 4; ++reg)
            sqkT[v][16 * w + quad * 4 + reg] = f2u(a[reg] + bb[reg]);
        }
      }
    }
    __syncthreads();
    // S3: logit accumulate for wave's (s_w, mtu): D[u][v] += q^T q... = A(q^T)·B(k)
    {
      short8 aQ = {0, 0, 0, 0, 0, 0, 0, 0};
      short8 bK0 = {0, 0, 0, 0, 0, 0, 0, 0}, bK1 = {0, 0, 0, 0, 0, 0, 0, 0};
      if (quad < 2) {  // K=16 real, upper half zero
        aQ  = *(const short8*)&sqkT[16 * mtu + m][16 * s_w + 8 * quad];
        bK0 = *(const short8*)&sqkT[m][32 + 16 * s_w + 8 * quad];
        bK1 = *(const short8*)&sqkT[16 + m][32 + 16 * s_w + 8 * quad];
      }
      accA0 = MFMA(aQ, bK0, accA0);
      accA1 = MFMA(aQ, bK1, accA1);
    }
    __syncthreads();
  }
  // export: rows u = 16*mtu + quad*4+reg, cols v = 16*nt + m
#pragma unroll
  for (int nt = 0; nt < 2; ++nt) {
    f32x4 a = nt ? accA1 : accA0;
#pragma unroll
    for (int reg = 0; reg < 4; ++reg) {
      int u = 16 * mtu + quad * 4 + reg, v = 16 * nt + m;
      if (u < 27 && v < 27)
        atomicAdd(&att[(n * 2 + s_w) * 729 + u * 27 + v], a[reg]);
    }
  }
}

// ---------------------------------------------------------------------------
// K1b: att = tanh(acc/6400)*alphas[s] + att0[s,u,v]   (in place)
// ---------------------------------------------------------------------------
__global__ __launch_bounds__(256) void k_att_fin(
    float* __restrict__ att, const float* __restrict__ alphas,
    const float* __restrict__ att0)
{
  int i = blockIdx.x * 256 + threadIdx.x;
  if (i >= 32 * 2 * 729) return;
  int s = (i / 729) & 1;
  int r = i % 729;
  att[i] = tanhf(att[i] * (1.f / 6400.f)) * alphas[s] + att0[s * 729 + r];
}

// ---------------------------------------------------------------------------
// K2 (MFMA fused): per block (n, 8 center t + 1 halo each side). 4 waves;
// wave w owns output-channel rows [16w,16w+16) in every stage.
//   per slice: A: y2 = x·att  -> B: y3 = lrelu(x+bn(W_out@y2))
//              -> C: y4 = lrelu(x+bn(W_ff@y3)) into rolling 3-slice window
//              -> D (center-1): z = lrelu(y4 + bn(conv3@y4)) -> global
// Weights as persistent register A-frags. LDS 32.2 KB.
// ---------------------------------------------------------------------------
__global__ __launch_bounds__(256) void k_fused_mfma(
    const float* __restrict__ x, const float* __restrict__ att,
    const float* __restrict__ W_out, const float* __restrict__ b_out,
    const float* __restrict__ g_out, const float* __restrict__ be_out,
    const float* __restrict__ m_out, const float* __restrict__ v_out,
    const float* __restrict__ W_ff, const float* __restrict__ b_ff,
    const float* __restrict__ g_ff, const float* __restrict__ be_ff,
    const float* __restrict__ m_ff, const float* __restrict__ v_ff,
    const float* __restrict__ W_t, const float* __restrict__ b_t,
    const float* __restrict__ g_t, const float* __restrict__ be_t,
    const float* __restrict__ m_t, const float* __restrict__ v_t,
    float* __restrict__ out)
{
  __shared__ u16 sx[64][40];      // x bf16 [c][u]; cols 27..39 zero
  __shared__ u16 sy2[32][136];    // y2^T [v][s*64+c]; rows 27..31 zero
  __shared__ u16 sy3[32][72];     // y3^T [v][c];      rows 27..31 zero
  __shared__ u16 sy4[3][32][72];  // y4^T rolling [sl%3][v][i]; rows 27..31 zero
  const int tid = threadIdx.x;
  const int w = tid >> 6, lane = tid & 63;
  const int m = lane & 15, quad = lane >> 4;
  const int n = blockIdx.y, t0 = blockIdx.x * 8;

  for (int i = tid; i < 64 * 40; i += 256) sx[0][i] = 0;
  for (int i = tid; i < 32 * 136; i += 256) sy2[0][i] = 0;
  for (int i = tid; i < 32 * 72; i += 256) sy3[0][i] = 0;
  for (int i = tid; i < 3 * 32 * 72; i += 256) sy4[0][0][i] = 0;

  // persistent weight A-frags (rows o = 16w + m)
  short8 aWo[4], aWf[2], aWt[6], bAtt[4];
#pragma unroll
  for (int kf = 0; kf < 4; ++kf) {
    short8 tt;
#pragma unroll
    for (int j = 0; j < 8; ++j)
      tt[j] = (short)f2u(W_out[(16 * w + m) * 128 + 32 * kf + 8 * quad + j]);
    aWo[kf] = tt;
  }
#pragma unroll
  for (int kf = 0; kf < 2; ++kf) {
    short8 tt;
#pragma unroll
    for (int j = 0; j < 8; ++j)
      tt[j] = (short)f2u(W_ff[(16 * w + m) * 64 + 32 * kf + 8 * quad + j]);
    aWf[kf] = tt;
  }
#pragma unroll
  for (int kf = 0; kf < 6; ++kf) {  // k = dt*64 + i
    short8 tt;
    int dt = kf >> 1;
#pragma unroll
    for (int j = 0; j < 8; ++j) {
      int ii = 32 * (kf & 1) + 8 * quad + j;
      tt[j] = (short)f2u(W_t[((16 * w + m) * 64 + ii) * 3 + dt]);
    }
    aWt[kf] = tt;
  }
#pragma unroll
  for (int s = 0; s < 2; ++s)
#pragma unroll
    for (int nt = 0; nt < 2; ++nt) {
      short8 tt;
#pragma unroll
      for (int j = 0; j < 8; ++j) {
        int u = 8 * quad + j, v = 16 * nt + m;
        tt[j] = (u < 27 && v < 27) ? (short)f2u(att[(n * 2 + s) * 729 + u * 27 + v]) : (short)0;
      }
      bAtt[s * 2 + nt] = tt;
    }
  // per-lane BN constants for rows o' = 16w + quad*4 + reg
  float Ao[4], Bo[4], Af[4], Bf[4], At[4], Bt[4];
#pragma unroll
  for (int reg = 0; reg < 4; ++reg) {
    int o = 16 * w + quad * 4 + reg;
    float sc;
    sc = g_out[o] * rsqrtf(v_out[o] + EPS_); Ao[reg] = sc; Bo[reg] = (b_out[o] - m_out[o]) * sc + be_out[o];
    sc = g_ff[o] * rsqrtf(v_ff[o] + EPS_);   Af[reg] = sc; Bf[reg] = (b_ff[o] - m_ff[o]) * sc + be_ff[o];
    sc = g_t[o] * rsqrtf(v_t[o] + EPS_);     At[reg] = sc; Bt[reg] = (b_t[o] - m_t[o]) * sc + be_t[o];
  }
  __syncthreads();

  for (int st = 0; st < 10; ++st) {
    const int t = t0 - 1 + st;
    const bool valid = (t >= 0) && (t < 400);
    // S1: stage x slice
    if (valid) {
      for (int i = tid; i < 1728; i += 256) {
        int c = i / 27, u = i % 27;
        sx[c][u] = f2u(x[((n * 64 + c) * 400 + t) * 27 + u]);
      }
    }
    __syncthreads();
    // S2: stage A (y2)
    if (valid) {
      short8 ax = *(const short8*)&sx[16 * w + m][8 * quad];
      f32x4 acc[4];
#pragma unroll
      for (int f = 0; f < 4; ++f) acc[f] = MFMA(ax, bAtt[f], z4());
#pragma unroll
      for (int s = 0; s < 2; ++s)
#pragma unroll
        for (int nt = 0; nt < 2; ++nt) {
          int v = 16 * nt + m;
          if (v < 27) {
            f32x4 a = acc[s * 2 + nt];
#pragma unroll
            for (int reg = 0; reg < 4; ++reg)
              sy2[v][s * 64 + 16 * w + quad * 4 + reg] = f2u(a[reg]);
          }
        }
    }
    __syncthreads();
    // S3: stage B (y3 = lrelu(x + bn(W_out@y2)))
    if (valid) {
      f32x4 a0 = z4(), a1 = z4();
#pragma unroll
      for (int kf = 0; kf < 4; ++kf) {
        short8 b0 = *(const short8*)&sy2[m][32 * kf + 8 * quad];
        short8 b1 = *(const short8*)&sy2[16 + m][32 * kf + 8 * quad];
        a0 = MFMA(aWo[kf], b0, a0);
        a1 = MFMA(aWo[kf], b1, a1);
      }
#pragma unroll
      for (int nt = 0; nt < 2; ++nt) {
        f32x4 a = nt ? a1 : a0;
        int v = 16 * nt + m;
        if (v < 27) {
#pragma unroll
          for (int reg = 0; reg < 4; ++reg) {
            int o = 16 * w + quad * 4 + reg;
            float r = u2f(sx[o][v]) + a[reg] * Ao[reg] + Bo[reg];
            sy3[v][o] = f2u((r >= 0.f) ? r : LEAK * r);
          }
        }
      }
    }
    __syncthreads();
    // S4: stage C (y4 = lrelu(x + bn(W_ff@y3))) into rolling window
    if (valid) {
      f32x4 a0 = z4(), a1 = z4();
#pragma unroll
      for (int kf = 0; kf < 2; ++kf) {
        short8 b0 = *(const short8*)&sy3[m][32 * kf + 8 * quad];
        short8 b1 = *(const short8*)&sy3[16 + m][32 * kf + 8 * quad];
        a0 = MFMA(aWf[kf], b0, a0);
        a1 = MFMA(aWf[kf], b1, a1);
      }
#pragma unroll
      for (int nt = 0; nt < 2; ++nt) {
        f32x4 a = nt ? a1 : a0;
        int v = 16 * nt + m;
        if (v < 27) {
#pragma unroll
          for (int reg = 0; reg < 4; ++reg) {
            int o = 16 * w + quad * 4 + reg;
            float r = u2f(sx[o][v]) + a[reg] * Af[reg] + Bf[reg];
            sy4[st % 3][v][o] = f2u((r >= 0.f) ? r : LEAK * r);
          }
        }
      }
    } else {
      for (int i = tid; i < 27 * 64; i += 256)
        sy4[st % 3][i / 64][i % 64] = 0;
    }
    __syncthreads();
    // S5: stage D for center slice (st-1): t_out = t0 + st - 2
    if (st >= 2) {
      f32x4 a0 = z4(), a1 = z4();
#pragma unroll
      for (int kf = 0; kf < 6; ++kf) {
        int sl = (st - 2 + (kf >> 1)) % 3;
        int col = 32 * (kf & 1) + 8 * quad;
        short8 b0 = *(const short8*)&sy4[sl][m][col];
        short8 b1 = *(const short8*)&sy4[sl][16 + m][col];
        a0 = MFMA(aWt[kf], b0, a0);
        a1 = MFMA(aWt[kf], b1, a1);
      }
      int t_out = t0 + st - 2;
#pragma unroll
      for (int nt = 0; nt < 2; ++nt) {
        f32x4 a = nt ? a1 : a0;
        int v = 16 * nt + m;
        if (v < 27) {
#pragma unroll
          for (int reg = 0; reg < 4; ++reg) {
            int o = 16 * w + quad * 4 + reg;
            float r = u2f(sy4[(st - 1) % 3][v][o]) + a[reg] * At[reg] + Bt[reg];
            out[((n * 64 + o) * 400 + t_out) * 27 + v] = (r >= 0.f) ? r : LEAK * r;
          }
        }
      }
    }
  }
}

// ---------------------------------------------------------------------------
extern "C" void kernel_launch(void* const* d_in, const int* in_sizes, int n_in,
                              void* d_out, int out_size, void* d_ws, size_t ws_size,
                              hipStream_t stream)
{
  const float* x      = (const float*)d_in[0];
  const float* pe     = (const float*)d_in[1];
  const float* W_in   = (const float*)d_in[2];
  const float* b_in   = (const float*)d_in[3];
  const float* alphas = (const float*)d_in[4];
  const float* att0   = (const float*)d_in[5];
  const float* W_out  = (const float*)d_in[6];
  const float* b_out  = (const float*)d_in[7];
  const float* g_out  = (const float*)d_in[8];
  const float* be_out = (const float*)d_in[9];
  const float* m_out  = (const float*)d_in[10];
  const float* v_out  = (const float*)d_in[11];
  const float* W_ff   = (const float*)d_in[12];
  const float* b_ff   = (const float*)d_in[13];
  const float* g_ff   = (const float*)d_in[14];
  const float* be_ff  = (const float*)d_in[15];
  const float* m_ff   = (const float*)d_in[16];
  const float* v_ff   = (const float*)d_in[17];
  const float* W_t    = (const float*)d_in[18];
  const float* b_t    = (const float*)d_in[19];
  const float* g_t    = (const float*)d_in[20];
  const float* be_t   = (const float*)d_in[21];
  const float* m_t    = (const float*)d_in[22];
  const float* v_t    = (const float*)d_in[23];

  float* att = (float*)d_ws;  // 32*2*729 floats = 186 KB — only ws use

  hipMemsetAsync(att, 0, 32 * 2 * 729 * sizeof(float), stream);
  k_att_mfma<<<dim3(25, 32), 256, 0, stream>>>(x, pe, W_in, b_in, att);
  k_att_fin<<<dim3((32 * 2 * 729 + 255) / 256), 256, 0, stream>>>(att, alphas, att0);
  k_fused_mfma<<<dim3(50, 32), 256, 0, stream>>>(
      x, att,
      W_out, b_out, g_out, be_out, m_out, v_out,
      W_ff, b_ff, g_ff, be_ff, m_ff, v_ff,
      W_t, b_t, g_t, be_t, m_t, v_t,
      (float*)d_out);
}